// Round 1
// baseline (123.708 us; speedup 1.0000x reference)
//
#include <hip/hip_runtime.h>
#include <hip/hip_bf16.h>

typedef __bf16 bf16_t;
typedef bf16_t bf16x8 __attribute__((ext_vector_type(8)));
typedef float f32x4 __attribute__((ext_vector_type(4)));

#define TH 16     // total heads
#define CH 4      // contextual heads
#define DD 64     // head dim
#define SJ 2048   // seq len (compile-time for LDS sizing; harness-fixed)

__device__ __forceinline__ float sigmoidf_(float x) {
    return 1.0f / (1.0f + __expf(-x));
}

// ---------------- Contextual heads: dots (MFMA) + sigmoid + row-scan + write
__global__ __launch_bounds__(256) void ctx_kernel(
    const float* __restrict__ q, const float* __restrict__ k,
    const float* __restrict__ cab, const int* __restrict__ offp,
    const int* __restrict__ prep, float* __restrict__ out, int S, int J)
{
    __shared__ float Sm[16][SJ];          // 128 KiB
    const int h    = blockIdx.y;          // 0..3
    const int r0   = blockIdx.x * 16;
    const int tid  = threadIdx.x;
    const int lane = tid & 63;
    const int w    = tid >> 6;            // wave id 0..3
    const int offset = offp[0];
    const int prefix = prep[0];

    const float* qh = q + (size_t)h * S * DD;
    const float* kh = k + (size_t)h * S * DD;

    // ---- Phase A: dots via mfma_f32_16x16x32_bf16, sigmoid -> Sm
    // A layout: row = lane&15, k = (lane>>4)*8 + e   (contiguous in d)
    bf16x8 afrag[2];
    {
        const int row   = r0 + (lane & 15);
        const int dbase = (lane >> 4) * 8;
        const float* qp = qh + (size_t)row * DD + dbase;
        #pragma unroll
        for (int kk = 0; kk < 2; ++kk) {
            f32x4 v0 = *(const f32x4*)(qp + kk * 32);
            f32x4 v1 = *(const f32x4*)(qp + kk * 32 + 4);
            #pragma unroll
            for (int e = 0; e < 4; ++e) {
                afrag[kk][e]     = (bf16_t)v0[e];
                afrag[kk][e + 4] = (bf16_t)v1[e];
            }
        }
    }
    // wave w owns cols [w*SJ/4, (w+1)*SJ/4)
    for (int ct = 0; ct < SJ / 64; ++ct) {
        const int c0 = w * (SJ / 4) + ct * 16;
        f32x4 acc = {0.f, 0.f, 0.f, 0.f};
        #pragma unroll
        for (int kk = 0; kk < 2; ++kk) {
            const int col   = c0 + (lane & 15);
            const int dbase = kk * 32 + (lane >> 4) * 8;
            const float* p  = kh + (size_t)col * DD + dbase;
            f32x4 v0 = *(const f32x4*)(p);
            f32x4 v1 = *(const f32x4*)(p + 4);
            bf16x8 bfrag;
            #pragma unroll
            for (int e = 0; e < 4; ++e) {
                bfrag[e]     = (bf16_t)v0[e];
                bfrag[e + 4] = (bf16_t)v1[e];
            }
            acc = __builtin_amdgcn_mfma_f32_16x16x32_bf16(afrag[kk], bfrag, acc, 0, 0, 0);
        }
        // D layout: col = lane&15, row = (lane>>4)*4 + m
        const int ccol  = c0 + (lane & 15);
        const int rbase = (lane >> 4) * 4;
        #pragma unroll
        for (int m = 0; m < 4; ++m)
            Sm[rbase + m][ccol] = sigmoidf_(acc[m] * 0.125f);
    }
    __syncthreads();

    // ---- Phase B: inclusive prefix scan of each row (wave w scans rows w*4..w*4+3)
    #pragma unroll
    for (int rr = 0; rr < 4; ++rr) {
        const int rl = w * 4 + rr;
        float carry = 0.f;
        for (int seg = 0; seg < SJ; seg += 64) {
            float x = Sm[rl][seg + lane];
            #pragma unroll
            for (int dlt = 1; dlt < 64; dlt <<= 1) {
                float y = __shfl_up(x, dlt);
                if (lane >= dlt) x += y;
            }
            x += carry;
            Sm[rl][seg + lane] = x;
            carry = __shfl(x, 63);
        }
    }
    __syncthreads();

    // ---- Phase C: produce output with cross-mask + slope
    const float slope = exp2f(-0.5f * (float)(h + 1));
    const float cabv  = cab[h];
    for (int r = 0; r < 16; ++r) {
        const float* Srow = &Sm[r][0];
        const int rg = r0 + r;
        const int dg = rg + offset;                 // diagonal column
        const int dgl = dg - 1;
        const float pdin = (dg  < 0) ? 0.f : Srow[dg  < J ? dg  : (J - 1)];
        const float pdex = (dgl < 0) ? 0.f : Srow[dgl < J ? dgl : (J - 1)];
        const bool  rpre = dg < prefix;
        float* orow = out + ((size_t)h * S + rg) * (size_t)J;
        for (int c0 = tid * 4; c0 < J; c0 += 256 * 4) {
            const f32x4 pin = *(const f32x4*)(Srow + c0);
            const float ex0 = (c0 == 0) ? 0.f : Srow[c0 - 1];
            const float exv[4] = {ex0, pin[0], pin[1], pin[2]};
            f32x4 o;
            #pragma unroll
            for (int e = 0; e < 4; ++e) {
                const int c = c0 + e;
                const float cpos = (c > dg) ? -(pin[e] - pdin)
                                 : (c < dg) ? -(pdex - exv[e]) : 0.f;
                const bool cross = rpre != (c < prefix);
                o[e] = cross ? cabv : slope * cpos;
            }
            *(f32x4*)(orow + c0) = o;
        }
    }
}

// ---------------- ALiBi heads 4..15: pure write
__global__ __launch_bounds__(256) void alibi_kernel(
    const float* __restrict__ cab, const int* __restrict__ offp,
    const int* __restrict__ prep, float* __restrict__ out, int S, int J)
{
    const int h  = CH + blockIdx.y;       // 4..15
    const int rg = blockIdx.x;
    const int offset = offp[0];
    const int prefix = prep[0];
    const float slope = exp2f(-0.5f * (float)(h + 1));
    const float cabv  = cab[h];
    const int dg = rg + offset;
    const bool rpre = dg < prefix;
    float* orow = out + ((size_t)h * S + rg) * (size_t)J;
    for (int c0 = (int)threadIdx.x * 4; c0 < J; c0 += 256 * 4) {
        f32x4 o;
        #pragma unroll
        for (int e = 0; e < 4; ++e) {
            const int c = c0 + e;
            const float v = -fabsf((float)(c - dg)) * slope;
            const bool cross = rpre != (c < prefix);
            o[e] = cross ? cabv : v;
        }
        *(f32x4*)(orow + c0) = o;
    }
}

extern "C" void kernel_launch(void* const* d_in, const int* in_sizes, int n_in,
                              void* d_out, int out_size, void* d_ws, size_t ws_size,
                              hipStream_t stream) {
    const float* q    = (const float*)d_in[0];
    const float* k    = (const float*)d_in[1];
    const float* cab  = (const float*)d_in[2];
    const int*   offp = (const int*)d_in[5];
    const int*   prep = (const int*)d_in[6];
    float* out = (float*)d_out;

    const int s = in_sizes[0] / (TH * DD);   // 2048
    const int J = s;
    if (s <= 0) return;

    ctx_kernel<<<dim3(s / 16, CH), 256, 0, stream>>>(q, k, cab, offp, prep, out, s, J);
    alibi_kernel<<<dim3(s, TH - CH), 256, 0, stream>>>(cab, offp, prep, out, s, J);
}

// Round 2
// 82.515 us; speedup vs baseline: 1.4992x; 1.4992x over previous
//
#include <hip/hip_runtime.h>
#include <hip/hip_bf16.h>

typedef __bf16 bf16_t;
typedef bf16_t bf16x8 __attribute__((ext_vector_type(8)));
typedef float f32x4 __attribute__((ext_vector_type(4)));

#define TH 16     // total heads
#define CH 4      // contextual heads
#define DD 64     // head dim
#define SJ 2048   // seq len (harness-fixed)
#define CTXB (SJ/16)                  // 128 ctx blocks per head
#define NCTX (CH*CTXB)                // 512
#define AROWS 8                       // alibi rows per block
#define NALIBI ((TH-CH)*(SJ/AROWS))   // 3072
#define NBLK (NCTX + NALIBI)          // 3584; ctx at bx%7==0

__device__ __forceinline__ float sigmoidf_(float x) {
    return 1.0f / (1.0f + __expf(-x));
}

__global__ __launch_bounds__(512, 4) void fused_kernel(
    const float* __restrict__ q, const float* __restrict__ k,
    const float* __restrict__ cab, const int* __restrict__ offp,
    const int* __restrict__ prep, float* __restrict__ out)
{
    __shared__ bf16_t Smb[16][SJ];        // 64 KiB -> 2 blocks/CU
    const int tid  = (int)threadIdx.x;
    const int lane = tid & 63;
    const int w    = tid >> 6;            // wave 0..7
    const int offset = offp[0];
    const int prefix = prep[0];
    const int bx = (int)blockIdx.x;

    if (bx % 7 == 0) {
        // ---------------- contextual head block: 16 rows ----------------
        const int id = bx / 7;            // 0..511
        const int h  = id >> 7;           // 0..3
        const int r0 = (id & (CTXB - 1)) << 4;
        const float* qh = q + (size_t)h * SJ * DD;
        const float* kh = k + (size_t)h * SJ * DD;

        // Phase A: dots via mfma_f32_16x16x32_bf16, sigmoid -> Smb (bf16)
        bf16x8 afrag[2];
        {
            const int row   = r0 + (lane & 15);
            const int dbase = (lane >> 4) * 8;
            const float* qp = qh + (size_t)row * DD + dbase;
            #pragma unroll
            for (int kk = 0; kk < 2; ++kk) {
                f32x4 v0 = *(const f32x4*)(qp + kk * 32);
                f32x4 v1 = *(const f32x4*)(qp + kk * 32 + 4);
                #pragma unroll
                for (int e = 0; e < 4; ++e) {
                    afrag[kk][e]     = (bf16_t)v0[e];
                    afrag[kk][e + 4] = (bf16_t)v1[e];
                }
            }
        }
        // wave w owns cols [w*256, (w+1)*256) : 16 tiles of 16
        for (int t = 0; t < 16; ++t) {
            const int c0 = w * 256 + t * 16;
            f32x4 acc = {0.f, 0.f, 0.f, 0.f};
            #pragma unroll
            for (int kk = 0; kk < 2; ++kk) {
                const int col = c0 + (lane & 15);
                const int db  = kk * 32 + (lane >> 4) * 8;
                const float* p = kh + (size_t)col * DD + db;
                f32x4 v0 = *(const f32x4*)(p);
                f32x4 v1 = *(const f32x4*)(p + 4);
                bf16x8 bfrag;
                #pragma unroll
                for (int e = 0; e < 4; ++e) {
                    bfrag[e]     = (bf16_t)v0[e];
                    bfrag[e + 4] = (bf16_t)v1[e];
                }
                acc = __builtin_amdgcn_mfma_f32_16x16x32_bf16(afrag[kk], bfrag, acc, 0, 0, 0);
            }
            const int ccol = c0 + (lane & 15);
            const int rb   = (lane >> 4) * 4;
            #pragma unroll
            for (int m = 0; m < 4; ++m)
                Smb[rb + m][ccol] = (bf16_t)sigmoidf_(acc[m] * 0.125f);
        }
        __syncthreads();

        // Phase B+C fused: wave w scans rows w*2, w*2+1; output from registers
        const float slope = exp2f(-0.5f * (float)(h + 1));
        const float cabv  = cab[h];
        for (int rr = 0; rr < 2; ++rr) {
            const int rl = w * 2 + rr;
            const int rg = r0 + rl;
            const int dg = rg + offset;
            const int cin = dg     < SJ ? dg     : (SJ - 1);
            const int cex = dg - 1 < SJ ? dg - 1 : (SJ - 1);
            float P[8][4], bse[8];
            float vin = 0.f, vex = 0.f, carry = 0.f;
            #pragma unroll
            for (int s = 0; s < 8; ++s) {
                const int cb = s * 256 + lane * 4;
                const unsigned long long u = *(const unsigned long long*)(&Smb[rl][cb]);
                float v[4];
                #pragma unroll
                for (int e = 0; e < 4; ++e)
                    v[e] = __uint_as_float((((unsigned int)(u >> (16 * e)) & 0xffffu) << 16));
                const float i0 = v[0], i1 = i0 + v[1], i2 = i1 + v[2], i3 = i2 + v[3];
                float x = i3;
                #pragma unroll
                for (int d = 1; d < 64; d <<= 1) {
                    float y = __shfl_up(x, d);
                    if (lane >= d) x += y;
                }
                const float base = carry + x - i3;
                bse[s]  = base;
                P[s][0] = base + i0; P[s][1] = base + i1;
                P[s][2] = base + i2; P[s][3] = base + i3;
                carry += __shfl(x, 63);
                #pragma unroll
                for (int e = 0; e < 4; ++e) {
                    const int c = cb + e;
                    if (c == cin) vin = P[s][e];
                    if (c == cex) vex = P[s][e];
                }
            }
            const float pdin = (dg >= 0) ? __shfl(vin, (cin >> 2) & 63) : 0.f;
            const float pdex = (dg >= 1) ? __shfl(vex, (cex >> 2) & 63) : 0.f;
            const bool rpre = dg < prefix;
            float* orow = out + ((size_t)h * SJ + rg) * (size_t)SJ;
            #pragma unroll
            for (int s = 0; s < 8; ++s) {
                const int cb = s * 256 + lane * 4;
                f32x4 o;
                #pragma unroll
                for (int e = 0; e < 4; ++e) {
                    const int c  = cb + e;
                    const float Pc = P[s][e];
                    const float Pm = (e == 0) ? bse[s] : P[s][e - 1];
                    const float cpos = (c > dg) ? -(Pc - pdin)
                                     : (c < dg) ? -(pdex - Pm) : 0.f;
                    const bool cross = (c < prefix) != rpre;
                    o[e] = cross ? cabv : slope * cpos;
                }
                *(f32x4*)(orow + cb) = o;
            }
        }
    } else {
        // ---------------- ALiBi head block: 8 rows, pure write ----------------
        const int id = bx - bx / 7 - 1;   // 0..3071
        const int h  = CH + (id >> 8);    // 4..15
        const int r0 = (id & 255) * AROWS;
        const float slope = exp2f(-0.5f * (float)(h + 1));
        const float cabv  = cab[h];
        const int rg = r0 + w;            // wave w -> one row
        const int dg = rg + offset;
        const bool rpre = dg < prefix;
        float* orow = out + ((size_t)h * SJ + rg) * (size_t)SJ;
        #pragma unroll
        for (int s = 0; s < 8; ++s) {
            const int cb = s * 256 + lane * 4;
            f32x4 o;
            #pragma unroll
            for (int e = 0; e < 4; ++e) {
                const int c = cb + e;
                const float v = -fabsf((float)(c - dg)) * slope;
                const bool cross = (c < prefix) != rpre;
                o[e] = cross ? cabv : v;
            }
            *(f32x4*)(orow + cb) = o;
        }
    }
}

extern "C" void kernel_launch(void* const* d_in, const int* in_sizes, int n_in,
                              void* d_out, int out_size, void* d_ws, size_t ws_size,
                              hipStream_t stream) {
    const float* q    = (const float*)d_in[0];
    const float* k    = (const float*)d_in[1];
    const float* cab  = (const float*)d_in[2];
    const int*   offp = (const int*)d_in[5];
    const int*   prep = (const int*)d_in[6];
    float* out = (float*)d_out;

    fused_kernel<<<dim3(NBLK), dim3(512), 0, stream>>>(q, k, cab, offp, prep, out);
}